// Round 4
// baseline (591.403 us; speedup 1.0000x reference)
//
#include <hip/hip_runtime.h>
#include <hip/hip_bf16.h>

#define N_NODES 20000
#define N_EDGES 320000
#define HD 512

typedef __attribute__((ext_vector_type(8))) short bf16x8;
typedef __attribute__((ext_vector_type(4))) float f32x4;

// ---------- bf16 helpers (RNE pack, cheap unpack) ----------
__device__ inline ushort f2bf(float f) {
    uint u = __float_as_uint(f);
    uint r = (u + 0x7fffu + ((u >> 16) & 1u)) >> 16;
    return (ushort)r;
}
__device__ inline uint pack2(float a, float b) {
    return (uint)f2bf(a) | ((uint)f2bf(b) << 16);
}
__device__ inline float bflo(uint u) { return __uint_as_float(u << 16); }
__device__ inline float bfhi(uint u) { return __uint_as_float(u & 0xffff0000u); }

// ---------- convert fp32 -> bf16, 8 elems/thread ----------
__global__ __launch_bounds__(256) void cvt_k(const float* __restrict__ in,
                                             ushort* __restrict__ out, int nchunk) {
    int c = blockIdx.x * 256 + threadIdx.x;
    if (c < nchunk) {
        const float4* p = (const float4*)in + (size_t)c * 2;
        float4 a = p[0], b = p[1];
        uint4 o;
        o.x = pack2(a.x, a.y); o.y = pack2(a.z, a.w);
        o.z = pack2(b.x, b.y); o.w = pack2(b.z, b.w);
        ((uint4*)out)[c] = o;
    }
}

// ---------- W [K][N] fp32 -> Wt [N][K] bf16 (LDS tile transpose) ----------
__global__ __launch_bounds__(256) void wt_k(const float* __restrict__ W0,
                                            const float* __restrict__ W1,
                                            const float* __restrict__ W2,
                                            ushort* __restrict__ T0,
                                            ushort* __restrict__ T1,
                                            ushort* __restrict__ T2) {
    const float* W = (blockIdx.z == 0) ? W0 : (blockIdx.z == 1) ? W1 : W2;
    ushort* T      = (blockIdx.z == 0) ? T0 : (blockIdx.z == 1) ? T1 : T2;
    __shared__ float t[64][65];
    int c = threadIdx.x & 63, r4 = threadIdx.x >> 6;
    int kb = blockIdx.x * 64, nb = blockIdx.y * 64;
    #pragma unroll
    for (int l = 0; l < 16; ++l) {
        int r = l * 4 + r4;
        t[r][c] = W[(size_t)(kb + r) * HD + nb + c];
    }
    __syncthreads();
    #pragma unroll
    for (int l = 0; l < 16; ++l) {
        int r = l * 4 + r4;
        T[(size_t)(nb + r) * HD + kb + c] = f2bf(t[c][r]);
    }
}

// ---------- bf16 MFMA GEMM: C[M,512] = A[M,512] * Bt[n][k]^T ----------
#define LDSK 40   // 32 + 8 pad: frag ds_read_b128 -> 2-way bank alias = free
__global__ __launch_bounds__(256) void gemm_bf16_k(const ushort* __restrict__ A,
                                                   const ushort* __restrict__ Bt,
                                                   ushort* __restrict__ C, int M) {
    __shared__ __align__(16) short As[128 * LDSK];
    __shared__ __align__(16) short Bs[128 * LDSK];
    const int tid = threadIdx.x;
    const int lane = tid & 63;
    const int wave = tid >> 6;
    const int l15 = lane & 15;
    const int q = lane >> 4;
    const int wrow = wave >> 1, wcol = wave & 1;
    const int row0 = blockIdx.y * 128;
    const int col0 = blockIdx.x * 128;

    f32x4 acc[4][4] = {};

    for (int k0 = 0; k0 < HD; k0 += 32) {
        #pragma unroll
        for (int l = 0; l < 2; ++l) {
            int c = tid + l * 256;          // 512 chunks of 8 bf16
            int row = c >> 2, kc = c & 3;
            uint4 v = make_uint4(0u, 0u, 0u, 0u);
            int gr = row0 + row;
            if (gr < M) v = *(const uint4*)&A[(size_t)gr * HD + k0 + kc * 8];
            *(uint4*)&As[row * LDSK + kc * 8] = v;
            uint4 w = *(const uint4*)&Bt[(size_t)(col0 + row) * HD + k0 + kc * 8];
            *(uint4*)&Bs[row * LDSK + kc * 8] = w;
        }
        __syncthreads();
        bf16x8 aF[4], bF[4];
        #pragma unroll
        for (int i = 0; i < 4; ++i)
            aF[i] = *(bf16x8*)&As[(wrow * 64 + i * 16 + l15) * LDSK + q * 8];
        #pragma unroll
        for (int j = 0; j < 4; ++j)
            bF[j] = *(bf16x8*)&Bs[(wcol * 64 + j * 16 + l15) * LDSK + q * 8];
        #pragma unroll
        for (int i = 0; i < 4; ++i)
            #pragma unroll
            for (int j = 0; j < 4; ++j)
                acc[i][j] = __builtin_amdgcn_mfma_f32_16x16x32_bf16(aF[i], bF[j], acc[i][j], 0, 0, 0);
        __syncthreads();
    }
    #pragma unroll
    for (int i = 0; i < 4; ++i) {
        #pragma unroll
        for (int r = 0; r < 4; ++r) {
            int gr = row0 + wrow * 64 + i * 16 + q * 4 + r;
            if (gr < M) {
                #pragma unroll
                for (int j = 0; j < 4; ++j) {
                    int gc = col0 + wcol * 64 + j * 16 + l15;
                    C[(size_t)gr * HD + gc] = f2bf(acc[i][j][r]);
                }
            }
        }
    }
}

// ---------- CSR build ----------
__global__ void hist_k(const int* __restrict__ rows, int* __restrict__ deg) {
    int e = blockIdx.x * blockDim.x + threadIdx.x;
    if (e < N_EDGES) atomicAdd(&deg[rows[e]], 1);
}

// one workgroup, 16 waves, shuffle-scan
__global__ __launch_bounds__(1024) void scan_k(const int* __restrict__ deg,
                                               int* __restrict__ rowstart,
                                               int* __restrict__ cursor) {
    __shared__ int wsum[16];
    const int tid = threadIdx.x;
    const int lane = tid & 63, wv = tid >> 6;
    int carry = 0;
    for (int base = 0; base < N_NODES; base += 1024) {
        int i = base + tid;
        int v = (i < N_NODES) ? deg[i] : 0;
        int incl = v;
        #pragma unroll
        for (int off = 1; off < 64; off <<= 1) {
            int t = __shfl_up(incl, off, 64);
            if (lane >= off) incl += t;
        }
        if (lane == 63) wsum[wv] = incl;
        __syncthreads();
        int woff = 0, tot = 0;
        #pragma unroll
        for (int w = 0; w < 16; ++w) {
            int sv = wsum[w];
            if (w < wv) woff += sv;
            tot += sv;
        }
        if (i < N_NODES) {
            int ex = carry + woff + incl - v;
            rowstart[i] = ex;
            cursor[i]   = ex;
        }
        carry += tot;
        __syncthreads();
    }
    if (tid == 0) rowstart[N_NODES] = carry;
}

__global__ void fill_k(const int* __restrict__ rows, const int* __restrict__ cols,
                       const float* __restrict__ vals, int* __restrict__ cursor,
                       int* __restrict__ csr_col, float* __restrict__ csr_val) {
    int e = blockIdx.x * blockDim.x + threadIdx.x;
    if (e < N_EDGES) {
        int p = atomicAdd(&cursor[rows[e]], 1);
        csr_col[p] = cols[e];
        csr_val[p] = vals[e];
    }
}

// ---------- aggregate, channel-chunked for L2 residency ----------
// grid (N_NODES/4, 8): chunk cz covers 64 channels = 32 uints = 128 B/row.
// Per-XCD working set = 20000*128B = 2.56 MB < 4 MiB L2.
// Half-wave per edge: lanes 0-31 even edges, 32-63 odd edges; 4B loads.
__global__ __launch_bounds__(256) void agg_k(const ushort* __restrict__ s,
                                             const int* __restrict__ rowstart,
                                             const int* __restrict__ csr_col,
                                             const float* __restrict__ csr_val,
                                             const float* __restrict__ bias,
                                             ushort* __restrict__ hout) {
    const int wave = threadIdx.x >> 6, lane = threadIdx.x & 63;
    const int half = lane >> 5;          // 0: even edges, 1: odd edges
    const int l32 = lane & 31;
    const int r = blockIdx.x * 4 + wave;
    const int cz = blockIdx.y;           // channel chunk
    const uint* su = (const uint*)s;     // row stride 256 uints
    const uint coff = cz * 32 + l32;     // uint offset within row

    const int beg = rowstart[r], end = rowstart[r + 1];
    const int P = end - beg;
    const int F = P >> 1;                // full pairs
    float a0 = 0.f, a1 = 0.f;

    int t = 0;
    for (; t + 4 <= F; t += 4) {
        int e = beg + 2 * t + half;
        int   c0 = csr_col[e],     c1 = csr_col[e + 2];
        int   c2 = csr_col[e + 4], c3 = csr_col[e + 6];
        float w0 = csr_val[e],     w1 = csr_val[e + 2];
        float w2 = csr_val[e + 4], w3 = csr_val[e + 6];
        uint v0 = su[(size_t)c0 * 256 + coff];
        uint v1 = su[(size_t)c1 * 256 + coff];
        uint v2 = su[(size_t)c2 * 256 + coff];
        uint v3 = su[(size_t)c3 * 256 + coff];
        a0 += w0 * bflo(v0); a1 += w0 * bfhi(v0);
        a0 += w1 * bflo(v1); a1 += w1 * bfhi(v1);
        a0 += w2 * bflo(v2); a1 += w2 * bfhi(v2);
        a0 += w3 * bflo(v3); a1 += w3 * bfhi(v3);
    }
    for (; t < F; ++t) {
        int e = beg + 2 * t + half;
        int   c0 = csr_col[e];
        float w0 = csr_val[e];
        uint v0 = su[(size_t)c0 * 256 + coff];
        a0 += w0 * bflo(v0); a1 += w0 * bfhi(v0);
    }
    if ((P & 1) && half == 0) {          // leftover edge (even slot)
        int e = beg + 2 * F;
        int   c0 = csr_col[e];
        float w0 = csr_val[e];
        uint v0 = su[(size_t)c0 * 256 + coff];
        a0 += w0 * bflo(v0); a1 += w0 * bfhi(v0);
    }
    // combine halves
    a0 += __shfl_xor(a0, 32);
    a1 += __shfl_xor(a1, 32);
    if (half == 0) {
        float2 b = ((const float2*)bias)[cz * 32 + l32];
        float o0 = fmaxf(a0 + b.x, 0.f);
        float o1 = fmaxf(a1 + b.y, 0.f);
        ((uint*)hout)[(size_t)r * 256 + coff] = pack2(o0, o1);
    }
}

// ---------- pool: per-channel max & sum (bf16 input) ----------
__global__ __launch_bounds__(256) void pool_k(const ushort* __restrict__ h,
                                              float* __restrict__ pmax,
                                              float* __restrict__ psum) {
    const int tid = threadIdx.x;
    const uint* h2 = (const uint*)h;
    float m0 = 0.f, m1 = 0.f, s0 = 0.f, s1 = 0.f;   // relu output >= 0
    for (int r = blockIdx.x; r < N_NODES; r += gridDim.x) {
        uint v = h2[(size_t)r * 256 + tid];
        float a = bflo(v), b = bfhi(v);
        m0 = fmaxf(m0, a); m1 = fmaxf(m1, b);
        s0 += a;           s1 += b;
    }
    atomicMax((int*)&pmax[tid * 2],     __float_as_int(m0));
    atomicMax((int*)&pmax[tid * 2 + 1], __float_as_int(m1));
    atomicAdd(&psum[tid * 2],     s0);
    atomicAdd(&psum[tid * 2 + 1], s1);
}

// ---------- head MLP + log_softmax ----------
__global__ __launch_bounds__(256) void mlp_k(const float* __restrict__ pool_max,
                                             const float* __restrict__ pool_sum,
                                             const float* __restrict__ l1W,
                                             const float* __restrict__ l1b,
                                             const float* __restrict__ l2W,
                                             const float* __restrict__ l2b,
                                             const float* __restrict__ l3W,
                                             const float* __restrict__ l3b,
                                             float* __restrict__ out) {
    __shared__ float g[1024];
    __shared__ float a1[128];
    __shared__ float a2[64];
    __shared__ float a3[10];
    const int tid = threadIdx.x;
    for (int c = tid; c < 512; c += 256) {
        g[c]       = pool_max[c] + pool_max[512 + c] + pool_max[1024 + c];
        g[512 + c] = (pool_sum[c] + pool_sum[512 + c] + pool_sum[1024 + c]) *
                     (1.0f / N_NODES);
    }
    __syncthreads();
    if (tid < 128) {
        float acc = l1b[tid];
        for (int k = 0; k < 1024; ++k) acc += g[k] * l1W[k * 128 + tid];
        a1[tid] = fmaxf(acc, 0.f);
    }
    __syncthreads();
    if (tid < 64) {
        float acc = l2b[tid];
        for (int k = 0; k < 128; ++k) acc += a1[k] * l2W[k * 64 + tid];
        a2[tid] = fmaxf(acc, 0.f);
    }
    __syncthreads();
    if (tid < 10) {
        float acc = l3b[tid];
        for (int k = 0; k < 64; ++k) acc += a2[k] * l3W[k * 10 + tid];
        a3[tid] = acc;
    }
    __syncthreads();
    if (tid == 0) {
        float m = a3[0];
        for (int j = 1; j < 10; ++j) m = fmaxf(m, a3[j]);
        float ssum = 0.f;
        for (int j = 0; j < 10; ++j) ssum += expf(a3[j] - m);
        float lse = m + logf(ssum);
        for (int j = 0; j < 10; ++j) out[j] = a3[j] - lse;
    }
}

extern "C" void kernel_launch(void* const* d_in, const int* in_sizes, int n_in,
                              void* d_out, int out_size, void* d_ws, size_t ws_size,
                              hipStream_t stream) {
    const float* x    = (const float*)d_in[0];
    const int*   rows = (const int*)  d_in[1];
    const int*   cols = (const int*)  d_in[2];
    const float* vals = (const float*)d_in[3];
    const float* W1   = (const float*)d_in[4];
    const float* b1   = (const float*)d_in[5];
    const float* W2   = (const float*)d_in[6];
    const float* b2   = (const float*)d_in[7];
    const float* W3   = (const float*)d_in[8];
    const float* b3   = (const float*)d_in[9];
    const float* l1W  = (const float*)d_in[10];
    const float* l1b  = (const float*)d_in[11];
    const float* l2W  = (const float*)d_in[12];
    const float* l2b  = (const float*)d_in[13];
    const float* l3W  = (const float*)d_in[14];
    const float* l3b  = (const float*)d_in[15];
    float* out = (float*)d_out;

    char* ws = (char*)d_ws;
    size_t off = 0;
    auto alloc = [&](size_t bytes) {
        void* p = ws + off;
        off += (bytes + 255) & ~(size_t)255;
        return p;
    };
    ushort* xb       = (ushort*)alloc((size_t)N_NODES * HD * 2);  // 20.5 MB
    ushort* s        = (ushort*)alloc((size_t)N_NODES * HD * 2);  // 20.5 MB
    ushort* hb       = (ushort*)alloc((size_t)N_NODES * HD * 2);  // 20.5 MB
    ushort* wt1      = (ushort*)alloc((size_t)HD * HD * 2);
    ushort* wt2      = (ushort*)alloc((size_t)HD * HD * 2);
    ushort* wt3      = (ushort*)alloc((size_t)HD * HD * 2);
    // --- zero-init span: deg + pmax + psum contiguous, one memset ---
    size_t zbase = off;
    int*    deg      = (int*)   alloc((size_t)N_NODES * 4);
    float*  pmax     = (float*) alloc((size_t)3 * 512 * 4);
    float*  psum     = (float*) alloc((size_t)3 * 512 * 4);
    size_t zlen = off - zbase;
    int*    rowstart = (int*)   alloc((size_t)(N_NODES + 1) * 4);
    int*    cursor   = (int*)   alloc((size_t)N_NODES * 4);
    int*    csr_col  = (int*)   alloc((size_t)N_EDGES * 4);
    float*  csr_val  = (float*) alloc((size_t)N_EDGES * 4);
    (void)ws_size; (void)in_sizes; (void)n_in; (void)out_size;

    hipMemsetAsync(ws + zbase, 0, zlen, stream);

    // prep: x -> bf16, W -> bf16 transposed, CSR build
    cvt_k<<<(N_NODES * HD / 8 + 255) / 256, 256, 0, stream>>>(x, xb, N_NODES * HD / 8);
    wt_k<<<dim3(8, 8, 3), 256, 0, stream>>>(W1, W2, W3, wt1, wt2, wt3);
    const int EB = (N_EDGES + 255) / 256;
    hist_k<<<EB, 256, 0, stream>>>(rows, deg);
    scan_k<<<1, 1024, 0, stream>>>(deg, rowstart, cursor);
    fill_k<<<EB, 256, 0, stream>>>(rows, cols, vals, cursor, csr_col, csr_val);

    dim3 ggrid(HD / 128, (N_NODES + 127) / 128);
    dim3 agrid(N_NODES / 4, 8);

    // layer 1
    gemm_bf16_k<<<ggrid, 256, 0, stream>>>(xb, wt1, s, N_NODES);
    agg_k<<<agrid, 256, 0, stream>>>(s, rowstart, csr_col, csr_val, b1, hb);
    pool_k<<<256, 256, 0, stream>>>(hb, pmax, psum);

    // layer 2
    gemm_bf16_k<<<ggrid, 256, 0, stream>>>(hb, wt2, s, N_NODES);
    agg_k<<<agrid, 256, 0, stream>>>(s, rowstart, csr_col, csr_val, b2, hb);
    pool_k<<<256, 256, 0, stream>>>(hb, pmax + 512, psum + 512);

    // layer 3
    gemm_bf16_k<<<ggrid, 256, 0, stream>>>(hb, wt3, s, N_NODES);
    agg_k<<<agrid, 256, 0, stream>>>(s, rowstart, csr_col, csr_val, b3, hb);
    pool_k<<<256, 256, 0, stream>>>(hb, pmax + 1024, psum + 1024);

    mlp_k<<<1, 256, 0, stream>>>(pmax, psum, l1W, l1b, l2W, l2b, l3W, l3b, out);
}